// Round 1
// baseline (8950.642 us; speedup 1.0000x reference)
//
#include <hip/hip_runtime.h>

// =====================================================================
// fp32 GEMMs emulated on bf16 matrix cores via hi/lo split (bf16x3):
//   x = hi + lo  (hi = RNE bf16, lo = bf16 of exact residual)
//   A*B ~= Ah*Bh + Ah*Bl + Al*Bh   (error ~2^-15 per product)
// MFMA: v_mfma_f32_16x16x32_bf16, fp32 accumulate.
// A/B fragments loaded with a CONSISTENT k-bijection (k = (lane>>4)*8+e,
// k-contiguous ds_read_b128) for both operands -> correct for any internal
// hardware k-permutation (pairing is symmetric between A and B).
// C/D layout (HW-verified): col = lane&15, row = (lane>>4)*4 + reg.
// =====================================================================

typedef unsigned short u16;
typedef unsigned int   u32;
typedef __attribute__((ext_vector_type(4))) float f32x4;
typedef __attribute__((ext_vector_type(8))) short bf16x8;

// ---------- fp32 -> bf16(hi) + bf16(lo), packed 2 per u32 ----------
__device__ __forceinline__ void cvt8(const float* f, uint4& hi, uint4& lo) {
    u32 h[8], l[8];
#pragma unroll
    for (int i = 0; i < 8; ++i) {
        u32 u  = __float_as_uint(f[i]);
        u32 hh = (u + 0x7FFFu + ((u >> 16) & 1u)) & 0xFFFF0000u;   // RNE to bf16
        h[i] = hh;
        l[i] = __float_as_uint(f[i] - __uint_as_float(hh));        // exact residual (Sterbenz)
    }
    hi = make_uint4(h[1] | (h[0] >> 16), h[3] | (h[2] >> 16),
                    h[5] | (h[4] >> 16), h[7] | (h[6] >> 16));
    lo = make_uint4((l[1] & 0xFFFF0000u) | (l[0] >> 16), (l[3] & 0xFFFF0000u) | (l[2] >> 16),
                    (l[5] & 0xFFFF0000u) | (l[4] >> 16), (l[7] & 0xFFFF0000u) | (l[6] >> 16));
}

// Stage a 64x32 tile from row-major src (rows = "own" dim, cols = k).
// LDS layout: T[row][kgroup^swz][8] bf16, swz = (row>>2)&3, 16B granules.
__device__ __forceinline__ void stage_rows(const float* __restrict__ src, int ld, int kb,
                                           u16 (*Th)[32], u16 (*Tl)[32], int lane) {
    const int tg = lane & 3, tm = lane >> 2;
#pragma unroll
    for (int ir = 0; ir < 4; ++ir) {
        const int rm = tm + 16 * ir;
        const float* p = src + (size_t)rm * ld + kb + tg * 8;
        float4 x0 = *(const float4*)p;
        float4 x1 = *(const float4*)(p + 4);
        float f[8] = {x0.x, x0.y, x0.z, x0.w, x1.x, x1.y, x1.z, x1.w};
        uint4 hi, lo;
        cvt8(f, hi, lo);
        const int pg = (tg ^ ((rm >> 2) & 3)) * 8;
        *(uint4*)&Th[rm][pg] = hi;
        *(uint4*)&Tl[rm][pg] = lo;
    }
}

// Stage a 64(n) x 32(k) tile from W[K][N] row-major (transpose into Bt[n][k]).
// nvalid guards the generator N-tail (OOB cols -> zeros).
__device__ __forceinline__ void stage_cols(const float* __restrict__ W, int ldw, int kb, int nvalid,
                                           u16 (*Th)[32], u16 (*Tl)[32], int lane) {
    float f[32];
    if (lane < nvalid) {
        const float* p = W + (size_t)kb * ldw + lane;
#pragma unroll
        for (int i = 0; i < 32; ++i) f[i] = p[(size_t)i * ldw];
    } else {
#pragma unroll
        for (int i = 0; i < 32; ++i) f[i] = 0.f;
    }
    const int swz = (lane >> 2) & 3;
#pragma unroll
    for (int g = 0; g < 4; ++g) {
        uint4 hi, lo;
        cvt8(&f[g * 8], hi, lo);
        const int pg = (g ^ swz) * 8;
        *(uint4*)&Th[lane][pg] = hi;
        *(uint4*)&Tl[lane][pg] = lo;
    }
}

// One 64x64x32 step: 16 positions x 3 mfma (hi*hi, hi*lo, lo*hi)
__device__ __forceinline__ void compute_tile(const u16 (*Ah)[32], const u16 (*Al)[32],
                                             const u16 (*Bh)[32], const u16 (*Bl)[32],
                                             int lane, f32x4 acc[4][4]) {
    const int lr = lane & 15, lg = lane >> 4;
    bf16x8 bh8[4], bl8[4];
#pragma unroll
    for (int j = 0; j < 4; ++j) {
        const int n  = j * 16 + lr;
        const int pg = (lg ^ ((n >> 2) & 3)) * 8;
        bh8[j] = *(const bf16x8*)&Bh[n][pg];
        bl8[j] = *(const bf16x8*)&Bl[n][pg];
    }
#pragma unroll
    for (int i = 0; i < 4; ++i) {
        const int m  = i * 16 + lr;
        const int pg = (lg ^ ((m >> 2) & 3)) * 8;
        bf16x8 ah = *(const bf16x8*)&Ah[m][pg];
        bf16x8 al = *(const bf16x8*)&Al[m][pg];
#pragma unroll
        for (int j = 0; j < 4; ++j) {
            acc[i][j] = __builtin_amdgcn_mfma_f32_16x16x32_bf16(ah, bh8[j], acc[i][j], 0, 0, 0);
            acc[i][j] = __builtin_amdgcn_mfma_f32_16x16x32_bf16(ah, bl8[j], acc[i][j], 0, 0, 0);
            acc[i][j] = __builtin_amdgcn_mfma_f32_16x16x32_bf16(al, bh8[j], acc[i][j], 0, 0, 0);
        }
    }
}

// =====================================================================
// General GEMM: C[M,N] = act(A[M,K] @ W[K,N] + bias (+res))
// 1 wave / block, 64x64 tile, BK=32.  SPLIT: fused QKV / KV — advance
// W (+262144), C (+2097152 = one ws slot), bias (+512) per 512-col matrix.
// =====================================================================
template<int RELU, int RES, int SPLIT>
__global__ __launch_bounds__(64, 2)
void mm_kernel(const float* __restrict__ A, int lda,
               const float* __restrict__ W, int ldw,
               const float* __restrict__ bias,
               const float* __restrict__ res, int ldres,
               float* __restrict__ C, int ldc,
               int M, int N, int K) {
    (void)M;
    __shared__ __align__(16) u16 Ah[64][32], Al[64][32], Bh[64][32], Bl[64][32];
    int n0 = blockIdx.x * 64;
    const int m0 = blockIdx.y * 64;
    if (SPLIT) {
        const int which = n0 >> 9;
        W    += (size_t)which * 262144;
        C    += (size_t)which * 2097152;
        bias += which * 512;
        n0   &= 511;
    }
    const int lane = threadIdx.x;
    const int nvalid = min(64, N - n0);
    const float* Ab = A + (size_t)m0 * lda;
    const float* Wb = W + n0;

    f32x4 acc[4][4];
#pragma unroll
    for (int i = 0; i < 4; ++i)
#pragma unroll
        for (int j = 0; j < 4; ++j) {
            acc[i][j][0] = 0.f; acc[i][j][1] = 0.f; acc[i][j][2] = 0.f; acc[i][j][3] = 0.f;
        }

    for (int kb = 0; kb < K; kb += 32) {
        stage_rows(Ab, lda, kb, Ah, Al, lane);
        stage_cols(Wb, ldw, kb, nvalid, Bh, Bl, lane);
        compute_tile(Ah, Al, Bh, Bl, lane, acc);   // single wave: DS pipe is in-order
    }

    const int lr = lane & 15, lq = lane >> 4;
#pragma unroll
    for (int i = 0; i < 4; ++i) {
        const int rb = m0 + i * 16 + lq * 4;
#pragma unroll
        for (int j = 0; j < 4; ++j) {
            const int col = n0 + j * 16 + lr;
            if (col < N) {
                const float bz = bias[col];
#pragma unroll
                for (int r = 0; r < 4; ++r) {
                    float vv = acc[i][j][r] + bz;
                    if (RES) vv += res[(size_t)(rb + r) * ldres + col];
                    if (RELU) vv = vv > 0.f ? vv : 0.f;
                    C[(size_t)(rb + r) * ldc + col] = vv;
                }
            }
        }
    }
}

// =====================================================================
// Attention scores: Q@K^T / 8, masked. Both operands row-major in k.
// grid: (Sk/64, Sq/64, 16), 1 wave. scores indexed by LOCAL bh (chunk).
// =====================================================================
__global__ __launch_bounds__(64, 2)
void mm_scores(const float* __restrict__ q, const float* __restrict__ kmat,
               const int* __restrict__ mask, float* __restrict__ scores,
               int Sq, int Sk, int bh0) {
    __shared__ __align__(16) u16 Ah[64][32], Al[64][32], Bh[64][32], Bl[64][32];
    const int lane = threadIdx.x;
    const int bhl = blockIdx.z, bhg = bh0 + bhl, b = bhg >> 3, h = bhg & 7;
    const int i0 = blockIdx.y * 64, j0 = blockIdx.x * 64;
    const float* Ab = q    + (size_t)(b * Sq + i0) * 512 + h * 64;
    const float* Bb = kmat + (size_t)(b * Sk + j0) * 512 + h * 64;

    f32x4 acc[4][4];
#pragma unroll
    for (int i = 0; i < 4; ++i)
#pragma unroll
        for (int j = 0; j < 4; ++j) {
            acc[i][j][0] = 0.f; acc[i][j][1] = 0.f; acc[i][j][2] = 0.f; acc[i][j][3] = 0.f;
        }

#pragma unroll
    for (int kb = 0; kb < 64; kb += 32) {
        stage_rows(Ab, 512, kb, Ah, Al, lane);
        stage_rows(Bb, 512, kb, Bh, Bl, lane);   // K rows are k-contiguous too
        compute_tile(Ah, Al, Bh, Bl, lane, acc);
    }

    const int lr = lane & 15, lq = lane >> 4;
#pragma unroll
    for (int i = 0; i < 4; ++i) {
        const int gi = i0 + i * 16 + lq * 4;
#pragma unroll
        for (int j = 0; j < 4; ++j) {
            const int gj = j0 + j * 16 + lr;
            const int mok = mask[b * Sk + gj];
#pragma unroll
            for (int r = 0; r < 4; ++r) {
                float s = acc[i][j][r] * 0.125f;
                if (mok == 0) s = -1e9f;
                scores[((size_t)bhl * Sq + gi) * Sk + gj] = s;
            }
        }
    }
}

// =====================================================================
// P@V: out[b, i, h*64+n] = sum_j p[bhl,i,j] * v[b,j,h*64+n]
// N=64 only -> 2-wave K-split (each wave Sk/2) + LDS reduction.
// grid: (Sq/64, 16), block 128.
// =====================================================================
__global__ __launch_bounds__(128, 2)
void mm_pv(const float* __restrict__ scores, const float* __restrict__ vmat,
           float* __restrict__ out, int Sq, int Sk, int bh0) {
    __shared__ __align__(16) u16 stg[2][4][64][32];   // 32 KB; wave1's half doubles as f32 reduce buf
    const int tid = threadIdx.x, lane = tid & 63, w = tid >> 6;
    const int bhl = blockIdx.y, bhg = bh0 + bhl, b = bhg >> 3, h = bhg & 7;
    const int i0 = blockIdx.x * 64;
    u16 (*Ah)[32] = stg[w][0];
    u16 (*Al)[32] = stg[w][1];
    u16 (*Bh)[32] = stg[w][2];
    u16 (*Bl)[32] = stg[w][3];
    const float* Ab = scores + (size_t)bhl * Sq * Sk + (size_t)i0 * Sk;
    const float* Wb = vmat + (size_t)b * Sk * 512 + h * 64;

    f32x4 acc[4][4];
#pragma unroll
    for (int i = 0; i < 4; ++i)
#pragma unroll
        for (int j = 0; j < 4; ++j) {
            acc[i][j][0] = 0.f; acc[i][j][1] = 0.f; acc[i][j][2] = 0.f; acc[i][j][3] = 0.f;
        }

    const int kbase = w * (Sk >> 1);
    for (int kk = 0; kk < (Sk >> 1); kk += 32) {
        const int kb = kbase + kk;
        stage_rows(Ab, Sk, kb, Ah, Al, lane);
        stage_cols(Wb, 512, kb, 64, Bh, Bl, lane);
        compute_tile(Ah, Al, Bh, Bl, lane, acc);
    }

    __syncthreads();
    const int lr = lane & 15, lq = lane >> 4;
    if (w == 1) {
        float* red = (float*)stg[1];
#pragma unroll
        for (int i = 0; i < 4; ++i)
#pragma unroll
            for (int j = 0; j < 4; ++j)
#pragma unroll
                for (int r = 0; r < 4; ++r)
                    red[(i * 16 + lq * 4 + r) * 64 + j * 16 + lr] = acc[i][j][r];
    }
    __syncthreads();
    if (w == 0) {
        const float* red = (const float*)stg[1];
#pragma unroll
        for (int i = 0; i < 4; ++i) {
            const int rl = i * 16 + lq * 4;
#pragma unroll
            for (int j = 0; j < 4; ++j) {
                const int cl = j * 16 + lr;
#pragma unroll
                for (int r = 0; r < 4; ++r) {
                    float vv = acc[i][j][r] + red[(rl + r) * 64 + cl];
                    out[(size_t)(b * Sq + i0 + rl + r) * 512 + h * 64 + cl] = vv;
                }
            }
        }
    }
}

// =============================================================
// Embedding: out[b,s,d] = emb[tok[b,s], d]*sqrt(512) + pe[s,d]
// =============================================================
__global__ void embed_kernel(const int* __restrict__ tok, const float* __restrict__ emb,
                             const float* __restrict__ pe, float* __restrict__ out,
                             int S, int total) {
    int i = blockIdx.x * 256 + threadIdx.x;
    if (i >= total) return;
    int d  = i & 511;
    int bs = i >> 9;
    int s  = bs % S;
    int t  = tok[bs];
    out[i] = emb[(size_t)t * 512 + d] * 22.62741699796952f + pe[(size_t)s * 512 + d];
}

// =============================================================
// LayerNorm (torch variant: unbiased std, divide by (std+eps))
// =============================================================
__global__ __launch_bounds__(256)
void layernorm_kernel(const float* __restrict__ x, const float* __restrict__ g,
                      const float* __restrict__ bta, float* __restrict__ out) {
    __shared__ float red[256];
    const int row = blockIdx.x, tid = threadIdx.x;
    const float* xr = x + (size_t)row * 512;
    float v0 = xr[tid], v1 = xr[tid + 256];
    red[tid] = v0 + v1;
    __syncthreads();
    for (int st = 128; st > 0; st >>= 1) { if (tid < st) red[tid] += red[tid + st]; __syncthreads(); }
    float mean = red[0] * (1.f / 512.f);
    __syncthreads();
    float d0 = v0 - mean, d1 = v1 - mean;
    red[tid] = d0 * d0 + d1 * d1;
    __syncthreads();
    for (int st = 128; st > 0; st >>= 1) { if (tid < st) red[tid] += red[tid + st]; __syncthreads(); }
    float var = red[0] * (1.f / 511.f);
    float inv = 1.f / (sqrtf(var) + 1e-6f);
    out[(size_t)row * 512 + tid]       = g[tid] * d0 * inv + bta[tid];
    out[(size_t)row * 512 + tid + 256] = g[tid + 256] * d1 * inv + bta[tid + 256];
}

// =============================================================
// Softmax over rows of length Sk==512 (one block per row), in place
// =============================================================
__global__ __launch_bounds__(256)
void softmax_kernel(float* __restrict__ p, int Sk) {
    __shared__ float red[256];
    const int row = blockIdx.x, tid = threadIdx.x;
    float* pr = p + (size_t)row * Sk;
    float v0 = pr[tid], v1 = pr[tid + 256];
    red[tid] = fmaxf(v0, v1);
    __syncthreads();
    for (int st = 128; st > 0; st >>= 1) { if (tid < st) red[tid] = fmaxf(red[tid], red[tid + st]); __syncthreads(); }
    float mx = red[0];
    __syncthreads();
    float e0 = __expf(v0 - mx), e1 = __expf(v1 - mx);
    red[tid] = e0 + e1;
    __syncthreads();
    for (int st = 128; st > 0; st >>= 1) { if (tid < st) red[tid] += red[tid + st]; __syncthreads(); }
    float inv = 1.f / red[0];
    pr[tid] = e0 * inv;
    pr[tid + 256] = e1 * inv;
}

// =============================================================
// In-place log_softmax on f32 rows of length N (one block/row)
// =============================================================
__global__ __launch_bounds__(256)
void logsoftmax_kernel(float* __restrict__ out, int N) {
    __shared__ float red[256];
    const int row = blockIdx.x, tid = threadIdx.x;
    float* pr = out + (size_t)row * N;
    float mx = -3.4e38f;
    for (int c = tid; c < N; c += 256) mx = fmaxf(mx, pr[c]);
    red[tid] = mx;
    __syncthreads();
    for (int st = 128; st > 0; st >>= 1) { if (tid < st) red[tid] = fmaxf(red[tid], red[tid + st]); __syncthreads(); }
    mx = red[0];
    __syncthreads();
    float s = 0.f;
    for (int c = tid; c < N; c += 256) s += __expf(pr[c] - mx);
    red[tid] = s;
    __syncthreads();
    for (int st = 128; st > 0; st >>= 1) { if (tid < st) red[tid] += red[tid + st]; __syncthreads(); }
    float ls = mx + __logf(red[0]);
    for (int c = tid; c < N; c += 256) pr[c] = pr[c] - ls;
}

// =============================================================
// Host orchestration — ws usage EXACTLY 64 MB (16,777,216 floats)
// ws slots (2,097,152 f each): x, h, q, k, v, mem | sf (4,194,304 f)
// q,k,v consecutive -> fused QKV / KV via SPLIT kernel.
// =============================================================
extern "C" void kernel_launch(void* const* d_in, const int* in_sizes, int n_in,
                              void* d_out, int out_size, void* d_ws, size_t ws_size,
                              hipStream_t stream) {
    const int*   src       = (const int*)d_in[0];
    const int*   tgt       = (const int*)d_in[1];
    const int*   src_mask  = (const int*)d_in[2];
    const float* emb_src   = (const float*)d_in[4];
    const float* emb_tgt   = (const float*)d_in[5];
    const float* pe        = (const float*)d_in[6];
    const float* enc_qkvo_w = (const float*)d_in[7];
    const float* enc_qkvo_b = (const float*)d_in[8];
    const float* enc_ff_w1  = (const float*)d_in[9];
    const float* enc_ff_b1  = (const float*)d_in[10];
    const float* enc_ff_w2  = (const float*)d_in[11];
    const float* enc_ff_b2  = (const float*)d_in[12];
    const float* enc_ln_g   = (const float*)d_in[13];
    const float* enc_ln_b   = (const float*)d_in[14];
    const float* enc_norm_g = (const float*)d_in[15];
    const float* enc_norm_b = (const float*)d_in[16];
    const float* dec_qkvo_w = (const float*)d_in[17];
    const float* dec_qkvo_b = (const float*)d_in[18];
    const float* dec_ff_w1  = (const float*)d_in[19];
    const float* dec_ff_b1  = (const float*)d_in[20];
    const float* dec_ff_w2  = (const float*)d_in[21];
    const float* dec_ff_b2  = (const float*)d_in[22];
    const float* dec_ln_g   = (const float*)d_in[23];
    const float* dec_ln_b   = (const float*)d_in[24];
    const float* dec_norm_g = (const float*)d_in[25];
    const float* dec_norm_b = (const float*)d_in[26];
    const float* gen_w      = (const float*)d_in[27];
    const float* gen_b      = (const float*)d_in[28];

    float* ws  = (float*)d_ws;
    float* x   = ws;
    float* h   = x + 2097152;
    float* q   = h + 2097152;      // slot 2  (QKV base; also ao)
    float* k   = q + 2097152;      // slot 3
    float* v   = k + 2097152;      // slot 4
    float* mem = v + 2097152;      // slot 5
    float* sf  = mem + 2097152;    // 4,194,304: attention scores chunk
    float* ao  = q;
    float* mid = q;                // FFN mid: enc 4096x2048 spans q..mem; dec 2048x2048 spans q..k

    // ---------------- encoder ----------------
    const int totE = 8 * 512 * 512;
    embed_kernel<<<totE / 256, 256, 0, stream>>>(src, emb_src, pe, x, 512, totE);

    for (int l = 0; l < 8; ++l) {
        const float* w    = enc_qkvo_w + (size_t)l * 4 * 262144;
        const float* bqkv = enc_qkvo_b + (size_t)l * 2048;
        layernorm_kernel<<<4096, 256, 0, stream>>>(x, enc_ln_g + (l * 2) * 512, enc_ln_b + (l * 2) * 512, h);
        // fused Q,K,V: N_eff = 1536, SPLIT walks w[0..2] / q,k,v / biases
        mm_kernel<0,0,1><<<dim3(24, 64), 64, 0, stream>>>(h, 512, w, 512, bqkv, nullptr, 0, q, 512, 4096, 512, 512);
        for (int c = 0; c < 4; ++c) {
            int bh0 = c * 16;
            mm_scores<<<dim3(8, 8, 16), 64, 0, stream>>>(q, k, src_mask, sf, 512, 512, bh0);
            softmax_kernel<<<16 * 512, 256, 0, stream>>>(sf, 512);
            mm_pv<<<dim3(8, 16), 128, 0, stream>>>(sf, v, ao, 512, 512, bh0);
        }
        mm_kernel<0,1,0><<<dim3(8, 64), 64, 0, stream>>>(ao, 512, w + 3 * 262144, 512, bqkv + 1536, x, 512, x, 512, 4096, 512, 512);
        layernorm_kernel<<<4096, 256, 0, stream>>>(x, enc_ln_g + (l * 2 + 1) * 512, enc_ln_b + (l * 2 + 1) * 512, h);
        mm_kernel<1,0,0><<<dim3(32, 64), 64, 0, stream>>>(h, 512, enc_ff_w1 + (size_t)l * 1048576, 2048, enc_ff_b1 + l * 2048, nullptr, 0, mid, 2048, 4096, 2048, 512);
        mm_kernel<0,1,0><<<dim3(8, 64), 64, 0, stream>>>(mid, 2048, enc_ff_w2 + (size_t)l * 1048576, 512, enc_ff_b2 + l * 512, x, 512, x, 512, 4096, 512, 2048);
    }
    layernorm_kernel<<<4096, 256, 0, stream>>>(x, enc_norm_g, enc_norm_b, mem);

    // ---------------- decoder (cross-attn + FFN only); y reuses x ----------------
    float* y = x;
    const int totD = 8 * 256 * 512;
    embed_kernel<<<totD / 256, 256, 0, stream>>>(tgt, emb_tgt, pe, y, 256, totD);

    for (int l = 0; l < 8; ++l) {
        const float* w    = dec_qkvo_w + (size_t)l * 4 * 262144;
        const float* bqkv = dec_qkvo_b + (size_t)l * 2048;
        layernorm_kernel<<<2048, 256, 0, stream>>>(y, dec_ln_g + (l * 2) * 512, dec_ln_b + (l * 2) * 512, h);
        mm_kernel<0,0,0><<<dim3(8, 32), 64, 0, stream>>>(h, 512, w, 512, bqkv, nullptr, 0, q, 512, 2048, 512, 512);
        // fused K,V from memory: N_eff = 1024 starting at w[1] / k / bias+512
        mm_kernel<0,0,1><<<dim3(16, 64), 64, 0, stream>>>(mem, 512, w + 262144, 512, bqkv + 512, nullptr, 0, k, 512, 4096, 512, 512);
        for (int c = 0; c < 4; ++c) {
            int bh0 = c * 16;
            mm_scores<<<dim3(8, 4, 16), 64, 0, stream>>>(q, k, src_mask, sf, 256, 512, bh0);
            softmax_kernel<<<16 * 256, 256, 0, stream>>>(sf, 512);
            mm_pv<<<dim3(4, 16), 128, 0, stream>>>(sf, v, ao, 256, 512, bh0);
        }
        mm_kernel<0,1,0><<<dim3(8, 32), 64, 0, stream>>>(ao, 512, w + 3 * 262144, 512, bqkv + 1536, y, 512, y, 512, 2048, 512, 512);
        layernorm_kernel<<<2048, 256, 0, stream>>>(y, dec_ln_g + (l * 2 + 1) * 512, dec_ln_b + (l * 2 + 1) * 512, h);
        mm_kernel<1,0,0><<<dim3(32, 32), 64, 0, stream>>>(h, 512, dec_ff_w1 + (size_t)l * 1048576, 2048, dec_ff_b1 + l * 2048, nullptr, 0, mid, 2048, 2048, 2048, 512);
        mm_kernel<0,1,0><<<dim3(8, 32), 64, 0, stream>>>(mid, 2048, dec_ff_w2 + (size_t)l * 1048576, 512, dec_ff_b2 + l * 512, y, 512, y, 512, 2048, 512, 2048);
    }
    layernorm_kernel<<<2048, 256, 0, stream>>>(y, dec_norm_g, dec_norm_b, h);

    // ---------------- generator + log_softmax ----------------
    float* out = (float*)d_out;
    mm_kernel<0,0,0><<<dim3(501, 32), 64, 0, stream>>>(h, 512, gen_w, 32001, gen_b, nullptr, 0, out, 32001, 2048, 32001, 512);
    logsoftmax_kernel<<<2048, 256, 0, stream>>>(out, 32001);
}